// Round 1
// baseline (2621.328 us; speedup 1.0000x reference)
//
#include <hip/hip_runtime.h>

// PrimaryCaps: 9x9 s2 VALID conv (16->49*8 ch) + bias + transpose + per-8 squash.
// Round 1: direct conv, f32, correctness-first baseline.
//
// Shapes: x[128,16,64,64], W[392,16,9,9], b[392]
// out[b, hw, oc] with oc = u*8+c  (this IS the reference's transposed layout:
//   out flat index = b*307328 + hw*392 + u*8 + c)

constexpr int Bn    = 128;
constexpr int Cin   = 16;
constexpr int Hin   = 64;
constexpr int Win   = 64;
constexpr int Units = 49;
constexpr int Cap   = 8;
constexpr int OW    = 28;
constexpr int HWp   = 784;            // 28*28
constexpr int K     = 9;
constexpr int KK    = Cin * K * K;    // 1296 (per-output-channel weight count)
constexpr int WperU = Cap * KK;       // 10368

__global__ __launch_bounds__(128) void pcaps_direct(
    const float* __restrict__ x,
    const float* __restrict__ W,
    const float* __restrict__ bias,
    float* __restrict__ out)
{
    const int blk  = blockIdx.x;
    const int tile = blk % 7;               // 7 hw-tiles of 128 (last partial)
    const int u    = (blk / 7) % Units;     // wave-uniform -> W loads scalarize
    const int b    = blk / (7 * Units);

    const int hw     = tile * 128 + threadIdx.x;
    const bool active = (hw < HWp);
    const int oy = active ? (hw / OW) : 0;
    const int ox = active ? (hw % OW) : 0;

    const float* __restrict__ xb = x + (size_t)b * (Cin * Hin * Win)
                                     + (size_t)(oy * 2) * Win + ox * 2;
    const float* __restrict__ wu = W + (size_t)u * WperU;

    float acc[Cap];
#pragma unroll
    for (int j = 0; j < Cap; ++j) acc[j] = bias[u * Cap + j];

    for (int c = 0; c < Cin; ++c) {
        const float* __restrict__ xc = xb + c * (Hin * Win);
        const float* __restrict__ wc = wu + c * (K * K);
#pragma unroll
        for (int ky = 0; ky < K; ++ky) {
            const float* __restrict__ xr = xc + ky * Win;
            float xv[K];
#pragma unroll
            for (int kx = 0; kx < K; ++kx) xv[kx] = xr[kx];   // contiguous; compiler merges
#pragma unroll
            for (int kx = 0; kx < K; ++kx) {
#pragma unroll
                for (int j = 0; j < Cap; ++j) {
                    // wc[...] is wave-uniform -> SGPR operand of v_fma_f32
                    acc[j] = fmaf(xv[kx], wc[j * KK + ky * K + kx], acc[j]);
                }
            }
        }
    }

    if (active) {
        float msq = 0.f;
#pragma unroll
        for (int j = 0; j < Cap; ++j) msq = fmaf(acc[j], acc[j], msq);
        // squash: s * |s| / (1 + |s|^2)
        const float scale = sqrtf(msq) / (1.0f + msq);

        float* __restrict__ op = out + (size_t)b * (HWp * Units * Cap)
                                     + (size_t)hw * (Units * Cap) + u * Cap;
        float4 o0, o1;
        o0.x = acc[0] * scale; o0.y = acc[1] * scale;
        o0.z = acc[2] * scale; o0.w = acc[3] * scale;
        o1.x = acc[4] * scale; o1.y = acc[5] * scale;
        o1.z = acc[6] * scale; o1.w = acc[7] * scale;
        *reinterpret_cast<float4*>(op)     = o0;   // 32B-aligned: (hw*392+u*8)*4
        *reinterpret_cast<float4*>(op + 4) = o1;
    }
}

extern "C" void kernel_launch(void* const* d_in, const int* in_sizes, int n_in,
                              void* d_out, int out_size, void* d_ws, size_t ws_size,
                              hipStream_t stream)
{
    const float* x  = (const float*)d_in[0];
    const float* W  = (const float*)d_in[1];
    const float* bs = (const float*)d_in[2];
    float* out      = (float*)d_out;

    const int grid = Bn * Units * 7;   // 43904 blocks x 128 threads
    pcaps_direct<<<grid, 128, 0, stream>>>(x, W, bs, out);
}

// Round 2
// 216.037 us; speedup vs baseline: 12.1337x; 12.1337x over previous
//
#include <hip/hip_runtime.h>

// PrimaryCaps as implicit GEMM on MFMA bf16.
//   out[m = b*784 + hw][n = u*8+c] = squash_8( conv )  -- n contiguous = GEMM C layout
//   M = 100352, N = 392 (pad 400), K = 1296 (pad 1312), k = (ky*9+kx)*16 + c
// A gathered on the fly from NHWC-bf16 x (prepacked in ws): each a-frag lane
// reads 8 consecutive channels = 16B contiguous. B prepacked per-fragment.

typedef __attribute__((ext_vector_type(8))) short short8;
typedef __attribute__((ext_vector_type(4))) float f32x4;

constexpr int Bn = 128, Cin = 16, HinW = 64;
constexpr int Units = 49, Cap = 8, OW = 28, HWp = 784;
constexpr int Nn = 392, Npad = 400;
constexpr int BM = 128, BNt = 80, NB = 5;      // 5 n-blocks of 80 cols
constexpr int NSTEP = 41;                      // K-steps of 32 (82 p-slots, p=81 zero)
constexpr size_t XW_BYTES = (size_t)Bn * 64 * 64 * 16 * 2;    // 16,777,216
constexpr size_t BW_BYTES = (size_t)NSTEP * 4 * Npad * 8 * 2; // 2,099,200

__device__ inline unsigned short f2bf(float f) {
    unsigned u = __float_as_uint(f);
    u += 0x7FFF + ((u >> 16) & 1);   // RNE (inputs finite)
    return (unsigned short)(u >> 16);
}

// ---- prep 1: x NCHW f32 -> NHWC bf16 ----------------------------------------
__global__ __launch_bounds__(256) void prep_x(const float* __restrict__ x,
                                              unsigned short* __restrict__ xw) {
    __shared__ unsigned short tile[64 * 16];   // [x][c]
    const int b = blockIdx.x >> 6, y = blockIdx.x & 63;
    const int t = threadIdx.x;                 // 256
    const int c = t >> 4, x0 = (t & 15) * 4;
    const float4 v = *(const float4*)(x + (((size_t)b * 16 + c) * 64 + y) * 64 + x0);
    tile[(x0 + 0) * 16 + c] = f2bf(v.x);
    tile[(x0 + 1) * 16 + c] = f2bf(v.y);
    tile[(x0 + 2) * 16 + c] = f2bf(v.z);
    tile[(x0 + 3) * 16 + c] = f2bf(v.w);
    __syncthreads();
    const ushort4 o = *(const ushort4*)&tile[t * 4];
    *(ushort4*)(xw + (size_t)blockIdx.x * 1024 + t * 4) = o;
}

// ---- prep 2: W [392][16][9][9] f32 -> B_ws[s][q][n][j] bf16 -----------------
__global__ __launch_bounds__(256) void prep_w(const float* __restrict__ W,
                                              unsigned short* __restrict__ bw) {
    const int idx = blockIdx.x * 256 + threadIdx.x;  // (s*4+q)*Npad + n
    if (idx >= NSTEP * 4 * Npad) return;
    const int n  = idx % Npad;
    const int sq = idx / Npad;
    const int q = sq & 3, s = sq >> 2;
    const int p = 2 * s + (q >> 1);
    const int c0 = (q & 1) * 8;
    unsigned short vals[8];
    if (p < 81 && n < Nn) {
        const int ky = p / 9, kx = p % 9;
#pragma unroll
        for (int j = 0; j < 8; ++j)
            vals[j] = f2bf(W[((size_t)(n * 16 + c0 + j) * 81) + ky * 9 + kx]);
    } else {
#pragma unroll
        for (int j = 0; j < 8; ++j) vals[j] = 0;
    }
    *(ushort4*)(bw + (size_t)idx * 8)     = make_ushort4(vals[0], vals[1], vals[2], vals[3]);
    *(ushort4*)(bw + (size_t)idx * 8 + 4) = make_ushort4(vals[4], vals[5], vals[6], vals[7]);
}

// ---- main: implicit GEMM + bias + squash ------------------------------------
__global__ __launch_bounds__(256) void pcaps_mfma(
    const unsigned short* __restrict__ xw,  // NHWC bf16
    const unsigned short* __restrict__ bw,  // packed B frags
    const float* __restrict__ bias,
    float* __restrict__ out)
{
    __shared__ int tbl[82];
    const int t = threadIdx.x;
    if (t < 82) {
        const int ky = t / 9, kx = t - ky * 9;
        tbl[t] = (t < 81) ? (ky * 2048 + kx * 32) : 0;   // byte offset into NHWC row
    }

    const int bid = blockIdx.x;
    const int nb = bid % NB;           // consecutive blocks share the x window
    const int mb = bid / NB;
    const int n0 = nb * BNt;
    const int w = t >> 6;              // wave 0..3 -> rows [w*32, w*32+32)
    const int l = t & 63;
    const int r = l & 15, q = l >> 4;

    // per-lane A base byte offsets (2 m-frags)
    int abase[2];
#pragma unroll
    for (int mi = 0; mi < 2; ++mi) {
        const int m = mb * BM + w * 32 + mi * 16 + r;
        const int b = m / HWp;
        const int hw = m - b * HWp;
        const int oy = hw / OW, ox = hw - oy * OW;
        abase[mi] = b * 131072 + oy * 4096 + ox * 64;
    }
    const int klane = (q & 1) * 16;       // byte offset of channel-half
    const int tidx0 = (l >> 5);           // which p of the pair
    int bbase = (q * Npad + n0 + r) * 16; // bytes; += 25600 per step

    f32x4 acc[2][5];
#pragma unroll
    for (int mi = 0; mi < 2; ++mi)
#pragma unroll
        for (int ni = 0; ni < 5; ++ni) acc[mi][ni] = (f32x4){0.f, 0.f, 0.f, 0.f};

    __syncthreads();

    const char* __restrict__ xc = (const char*)xw;
    const char* __restrict__ bc = (const char*)bw;

    for (int s = 0; s < NSTEP; ++s) {
        const int koff = tbl[2 * s + tidx0] + klane;

        short8 a[2];
#pragma unroll
        for (int mi = 0; mi < 2; ++mi)
            a[mi] = *(const short8*)(xc + (abase[mi] + koff));

        short8 bfr[5];
#pragma unroll
        for (int ni = 0; ni < 5; ++ni)
            bfr[ni] = *(const short8*)(bc + (bbase + ni * 256));
        bbase += 25600;

#pragma unroll
        for (int mi = 0; mi < 2; ++mi)
#pragma unroll
            for (int ni = 0; ni < 5; ++ni)
                acc[mi][ni] = __builtin_amdgcn_mfma_f32_16x16x32_bf16(
                    a[mi], bfr[ni], acc[mi][ni], 0, 0, 0);
    }

    // bias
    float bv[5];
#pragma unroll
    for (int ni = 0; ni < 5; ++ni) {
        const int n = n0 + ni * 16 + r;
        bv[ni] = (n < Nn) ? bias[n] : 0.f;
    }

    // squash groups of 8 cols (lanes sharing q and bit3 of r; xor over bits 0-2)
#pragma unroll
    for (int mi = 0; mi < 2; ++mi) {
#pragma unroll
        for (int ni = 0; ni < 5; ++ni) {
            const int n = n0 + ni * 16 + r;
#pragma unroll
            for (int reg = 0; reg < 4; ++reg) {
                float e = acc[mi][ni][reg] + bv[ni];
                float sq = e * e;
                sq += __shfl_xor(sq, 1);
                sq += __shfl_xor(sq, 2);
                sq += __shfl_xor(sq, 4);
                const float scale = sqrtf(sq) / (1.0f + sq);
                if (n < Nn) {
                    const int m = mb * BM + w * 32 + mi * 16 + q * 4 + reg;
                    out[(size_t)m * Nn + n] = e * scale;
                }
            }
        }
    }
}

// ---- fallback (round-1 direct conv, known-correct) --------------------------
__global__ __launch_bounds__(128) void pcaps_direct(
    const float* __restrict__ x, const float* __restrict__ W,
    const float* __restrict__ bias, float* __restrict__ out)
{
    const int blk = blockIdx.x;
    const int tile = blk % 7;
    const int u = (blk / 7) % Units;
    const int b = blk / (7 * Units);
    const int hw = tile * 128 + threadIdx.x;
    const bool active = (hw < HWp);
    const int oy = active ? (hw / OW) : 0;
    const int ox = active ? (hw % OW) : 0;
    const float* xb = x + (size_t)b * (Cin * 64 * 64) + (size_t)(oy * 2) * 64 + ox * 2;
    const float* wu = W + (size_t)u * (Cap * 1296);
    float acc[Cap];
#pragma unroll
    for (int j = 0; j < Cap; ++j) acc[j] = bias[u * Cap + j];
    for (int c = 0; c < Cin; ++c) {
        const float* xcp = xb + c * (64 * 64);
        const float* wc = wu + c * 81;
#pragma unroll
        for (int ky = 0; ky < 9; ++ky) {
            const float* xr = xcp + ky * 64;
            float xv[9];
#pragma unroll
            for (int kx = 0; kx < 9; ++kx) xv[kx] = xr[kx];
#pragma unroll
            for (int kx = 0; kx < 9; ++kx)
#pragma unroll
                for (int j = 0; j < Cap; ++j)
                    acc[j] = fmaf(xv[kx], wc[j * 1296 + ky * 9 + kx], acc[j]);
        }
    }
    if (active) {
        float msq = 0.f;
#pragma unroll
        for (int j = 0; j < Cap; ++j) msq = fmaf(acc[j], acc[j], msq);
        const float scale = sqrtf(msq) / (1.0f + msq);
        float* op = out + (size_t)b * (HWp * Nn) + (size_t)hw * Nn + u * Cap;
        float4 o0, o1;
        o0.x = acc[0] * scale; o0.y = acc[1] * scale; o0.z = acc[2] * scale; o0.w = acc[3] * scale;
        o1.x = acc[4] * scale; o1.y = acc[5] * scale; o1.z = acc[6] * scale; o1.w = acc[7] * scale;
        *reinterpret_cast<float4*>(op) = o0;
        *reinterpret_cast<float4*>(op + 4) = o1;
    }
}

extern "C" void kernel_launch(void* const* d_in, const int* in_sizes, int n_in,
                              void* d_out, int out_size, void* d_ws, size_t ws_size,
                              hipStream_t stream)
{
    const float* x  = (const float*)d_in[0];
    const float* W  = (const float*)d_in[1];
    const float* bs = (const float*)d_in[2];
    float* out      = (float*)d_out;

    if (ws_size < XW_BYTES + BW_BYTES) {
        pcaps_direct<<<Bn * Units * 7, 128, 0, stream>>>(x, W, bs, out);
        return;
    }

    unsigned short* xw = (unsigned short*)d_ws;
    unsigned short* bw = (unsigned short*)((char*)d_ws + XW_BYTES);

    prep_x<<<Bn * 64, 256, 0, stream>>>(x, xw);
    prep_w<<<(NSTEP * 4 * Npad + 255) / 256, 256, 0, stream>>>(W, bw);
    pcaps_mfma<<<784 * NB, 256, 0, stream>>>(xw, bw, bs, out);
}